// Round 3
// baseline (588.930 us; speedup 1.0000x reference)
//
#include <hip/hip_runtime.h>
#include <math.h>

#define NPIX (480*640)
#define NVOX 800000              // 100*100*80 voxels
#define MDIM 960
#define MPIX (MDIM*MDIM)
#define FIX_SH 20
#define FIX_SC 1048576.0f        // 2^20 fixed-point scale
#define SM_FLOATS 70000          // 7 planes * 10000
#define SCAL_FLOATS 16
#define NREP 8

// output layout (floats)
#define OUT_FPMAP 0
#define OUT_MAP   10000
#define OUT_POSE  (10000 + 9*MPIX)

__device__ __forceinline__ int get_xcc() {
    unsigned x;
    asm("s_getreg_b32 %0, hwreg(HW_REG_XCC_ID)" : "=s"(x));
    return (int)(x & 7);
}

__global__ void pose_kernel(const float* pose_obs, const float* poses_last,
                            float* scal, float* out_pose) {
    if (threadIdx.x == 0) {
        const float DEGc = 57.29577951308232f;
        float th = poses_last[2] / DEGc;
        float s = sinf(th), c = cosf(th);
        float ny = poses_last[1] + pose_obs[0]*s + pose_obs[1]*c;
        float nx = poses_last[0] + pose_obs[0]*c - pose_obs[1]*s;
        float nt = poses_last[2] + pose_obs[2]*DEGc;
        nt = fmodf(nt - 180.0f, 360.0f) + 180.0f;
        nt = fmodf(nt + 180.0f, 360.0f) - 180.0f;
        out_pose[0] = nx; out_pose[1] = ny; out_pose[2] = nt;
        out_pose[3] = nx; out_pose[4] = ny; out_pose[5] = nt;
        float sx = -((nx*100.0f)/5.0f - 480.0f)/480.0f;
        float sy = -((ny*100.0f)/5.0f - 480.0f)/480.0f;
        float sth = ((90.0f - nt) * 3.14159265358979323846f) / 180.0f;
        scal[0] = cosf(sth);
        scal[1] = sinf(sth);
        scal[2] = sx;
        scal[3] = sy;
    }
}

__global__ void ks_kernel(const float* __restrict__ obs, float* scal) {
    int tid = blockIdx.x*blockDim.x + threadIdx.x;
    int stride = gridDim.x*blockDim.x;
    float m0 = 0.0f, m1 = 0.0f, m2 = 0.0f, m3 = 0.0f;  // obs values are >= 0
    for (int p = tid; p < NPIX; p += stride) {
        m0 = fmaxf(m0, obs[4*NPIX + p]);
        m1 = fmaxf(m1, obs[5*NPIX + p]);
        m2 = fmaxf(m2, obs[6*NPIX + p]);
        m3 = fmaxf(m3, obs[7*NPIX + p]);
    }
    #pragma unroll
    for (int off = 32; off > 0; off >>= 1) {
        m0 = fmaxf(m0, __shfl_down(m0, off, 64));
        m1 = fmaxf(m1, __shfl_down(m1, off, 64));
        m2 = fmaxf(m2, __shfl_down(m2, off, 64));
        m3 = fmaxf(m3, __shfl_down(m3, off, 64));
    }
    if ((threadIdx.x & 63) == 0) {
        atomicMax((int*)&scal[4], __float_as_int(m0));
        atomicMax((int*)&scal[5], __float_as_int(m1));
        atomicMax((int*)&scal[6], __float_as_int(m2));
        atomicMax((int*)&scal[7], __float_as_int(m3));
    }
}

__device__ __forceinline__ unsigned long long pack2(float a, float b) {
    unsigned int la = __float2uint_rn(a * FIX_SC);
    unsigned int lb = __float2uint_rn(b * FIX_SC);
    return (unsigned long long)la | ((unsigned long long)lb << 32);
}

// common geometry: returns pos0..2 floors and feature values
__device__ __forceinline__ void pix_geom(const float* __restrict__ obs, int pix,
                                         float fcam,
                                         float& pos0, float& pos1, float& pos2,
                                         float* ft) {
    int i = pix / 640, j = pix - i*640;
    float d = obs[3*NPIX + pix];
    float X = ((float)j - 319.5f) * d / fcam + 250.0f;
    float Z = ((float)(479 - i) - 239.5f) * d / fcam + 88.0f;
    float xs = ((X/5.0f - 50.0f)/100.0f)*2.0f;
    float ys = ((d/5.0f - 50.0f)/100.0f)*2.0f;
    float zs = ((Z/5.0f - 32.0f)/80.0f)*2.0f;
    pos0 = (xs*100.0f)/2.0f + 50.0f;
    pos1 = (ys*100.0f)/2.0f + 50.0f;
    pos2 = (zs*80.0f)/2.0f + 40.0f;
    ft[0] = obs[4*NPIX + pix];
    ft[1] = obs[5*NPIX + pix];
    ft[2] = obs[6*NPIX + pix];
    ft[3] = obs[7*NPIX + pix];
    ft[4] = obs[8*NPIX + pix];
}

// replicated path: XCD-private grid + workgroup-scope atomics (stay in local TCC)
__global__ __launch_bounds__(256) void splat_kernel_rep(const float* __restrict__ obs,
                                                        unsigned long long* __restrict__ grid,
                                                        float fcam) {
    int pix = blockIdx.x*blockDim.x + threadIdx.x;
    if (pix >= NPIX) return;
    unsigned long long* rep = grid + (size_t)get_xcc() * NVOX * 3;
    float pos0, pos1, pos2, ft[5];
    pix_geom(obs, pix, fcam, pos0, pos1, pos2, ft);
    float f0 = floorf(pos0), f1 = floorf(pos1), f2 = floorf(pos2);
    #pragma unroll
    for (int c0 = 0; c0 <= 1; c0++) {
        float p0 = f0 + (float)c0;
        if (!(p0 > 0.0f && p0 < 100.0f)) continue;
        float w0 = 1.0f - fabsf(pos0 - p0);
        #pragma unroll
        for (int c1 = 0; c1 <= 1; c1++) {
            float p1 = f1 + (float)c1;
            if (!(p1 > 0.0f && p1 < 100.0f)) continue;
            float w01 = w0 * (1.0f - fabsf(pos1 - p1));
            #pragma unroll
            for (int c2 = 0; c2 <= 1; c2++) {
                float p2 = f2 + (float)c2;
                if (!(p2 > 0.0f && p2 < 80.0f)) continue;
                float w = w01 * (1.0f - fabsf(pos2 - p2));
                int idx = (((int)p0)*100 + (int)p1)*80 + (int)p2;
                unsigned long long* g = rep + (size_t)idx * 3;
                __hip_atomic_fetch_add(&g[0], pack2(w,       w*ft[0]),
                                       __ATOMIC_RELAXED, __HIP_MEMORY_SCOPE_WORKGROUP);
                __hip_atomic_fetch_add(&g[1], pack2(w*ft[1], w*ft[2]),
                                       __ATOMIC_RELAXED, __HIP_MEMORY_SCOPE_WORKGROUP);
                __hip_atomic_fetch_add(&g[2], pack2(w*ft[3], w*ft[4]),
                                       __ATOMIC_RELAXED, __HIP_MEMORY_SCOPE_WORKGROUP);
            }
        }
    }
}

// fallback: single grid, device-scope atomics (round-2 behavior)
__global__ __launch_bounds__(256) void splat_kernel(const float* __restrict__ obs,
                                                    unsigned long long* __restrict__ grid,
                                                    float fcam) {
    int pix = blockIdx.x*blockDim.x + threadIdx.x;
    if (pix >= NPIX) return;
    float pos0, pos1, pos2, ft[5];
    pix_geom(obs, pix, fcam, pos0, pos1, pos2, ft);
    float f0 = floorf(pos0), f1 = floorf(pos1), f2 = floorf(pos2);
    #pragma unroll
    for (int c0 = 0; c0 <= 1; c0++) {
        float p0 = f0 + (float)c0;
        if (!(p0 > 0.0f && p0 < 100.0f)) continue;
        float w0 = 1.0f - fabsf(pos0 - p0);
        #pragma unroll
        for (int c1 = 0; c1 <= 1; c1++) {
            float p1 = f1 + (float)c1;
            if (!(p1 > 0.0f && p1 < 100.0f)) continue;
            float w01 = w0 * (1.0f - fabsf(pos1 - p1));
            #pragma unroll
            for (int c2 = 0; c2 <= 1; c2++) {
                float p2 = f2 + (float)c2;
                if (!(p2 > 0.0f && p2 < 80.0f)) continue;
                float w = w01 * (1.0f - fabsf(pos2 - p2));
                int idx = (((int)p0)*100 + (int)p1)*80 + (int)p2;
                unsigned long long* g = grid + (size_t)idx * 3;
                atomicAdd(&g[0], pack2(w,       w*ft[0]));
                atomicAdd(&g[1], pack2(w*ft[1], w*ft[2]));
                atomicAdd(&g[2], pack2(w*ft[3], w*ft[4]));
            }
        }
    }
}

__device__ __forceinline__ unsigned int rnd_lo(unsigned long long g) {
    return (unsigned int)(((g & 0xFFFFFFFFull) + (1ull << (FIX_SH-1))) >> FIX_SH);
}
__device__ __forceinline__ unsigned int rnd_hi(unsigned long long g) {
    return (unsigned int)(((g >> 32) + (1ull << (FIX_SH-1))) >> FIX_SH);
}

// nrep replicas are merged with exact u64 adds (fields can't carry: each < 2^31)
__global__ void reduce_kernel(const unsigned long long* __restrict__ grid,
                              float* __restrict__ sm, float* __restrict__ out_fp,
                              int nrep) {
    int t = blockIdx.x*blockDim.x + threadIdx.x;
    if (t >= 10000) return;
    int r = t / 100, c = t - r*100;      // r = Y index, c = X index
    int vbase = (c*100 + r)*80;          // voxel flat = (X*100 + Y)*80 + z
    unsigned int ahp[6] = {0,0,0,0,0,0};
    unsigned int all0 = 0;
    for (int z = 0; z < 80; z++) {
        size_t off = (size_t)(vbase + z) * 3;
        unsigned long long g0 = 0, g1 = 0, g2 = 0;
        for (int rep = 0; rep < nrep; rep++) {
            const unsigned long long* g = grid + (size_t)rep * NVOX * 3 + off;
            g0 += g[0];
            if (z >= 13 && z < 25) { g1 += g[1]; g2 += g[2]; }
        }
        unsigned int cnt0 = rnd_lo(g0);
        all0 += cnt0;
        if (z >= 13 && z < 25) {
            ahp[0] += cnt0;
            ahp[1] += rnd_hi(g0);
            ahp[2] += rnd_lo(g1);
            ahp[3] += rnd_hi(g1);
            ahp[4] += rnd_lo(g2);
            ahp[5] += rnd_hi(g2);
        }
    }
    float fp = fminf((float)ahp[0], 1.0f);
    float ex = fminf((float)all0, 1.0f);
    sm[0*10000 + t] = fp;
    sm[1*10000 + t] = ex;
    #pragma unroll
    for (int k = 0; k < 5; k++)
        sm[(2+k)*10000 + t] = fminf((float)ahp[k+1]/5.0f, 1.0f);
    out_fp[t] = fp;
}

// bilinear sample of the (implicit, mostly-zero) agent_view at normalized coords,
// accumulating the 7 nonzero channels [0,1,4,5,6,7,8] from the small maps.
__device__ __forceinline__ void sample_agent(float gxv, float gyv,
                                             float ct, float sn,
                                             const float* __restrict__ sm,
                                             float rot[7]) {
    float u = ct*gxv - sn*gyv;
    float v = sn*gxv + ct*gyv;
    float xim = ((u + 1.0f)*0.5f)*959.0f;
    float yim = ((v + 1.0f)*0.5f)*959.0f;
    float x0 = floorf(xim), y0 = floorf(yim);
    #pragma unroll
    for (int ty = 0; ty <= 1; ty++) {
        float yy = y0 + (float)ty;
        if (yy < 480.0f || yy >= 580.0f) continue;   // region rows [480,580)
        float wy = 1.0f - fabsf(yim - yy);
        int yi = (int)yy - 480;
        #pragma unroll
        for (int tx = 0; tx <= 1; tx++) {
            float xx = x0 + (float)tx;
            if (xx < 430.0f || xx >= 530.0f) continue;  // region cols [430,530)
            float w = (1.0f - fabsf(xim - xx)) * wy;
            int o = yi*100 + ((int)xx - 430);
            #pragma unroll
            for (int k = 0; k < 7; k++) rot[k] += sm[k*10000 + o] * w;
        }
    }
}

__global__ __launch_bounds__(256) void final_kernel(const float* __restrict__ maps_last,
                                                    const float* __restrict__ sm,
                                                    const float* __restrict__ scal,
                                                    float* __restrict__ out_map) {
    int t = blockIdx.x*blockDim.x + threadIdx.x;
    if (t >= MPIX) return;
    int y = t / MDIM, x = t - y*MDIM;
    float ct = scal[0], sn = scal[1], sx = scal[2], sy = scal[3];
    float ks0 = scal[4], ks1 = scal[5], ks2 = scal[6], ks3 = scal[7];
    const float step = 2.0f/959.0f;
    float gxv = (float)x*step - 1.0f;
    float gyv = (float)y*step - 1.0f;
    float u = gxv + sx, v = gyv + sy;
    float xim = ((u + 1.0f)*0.5f)*959.0f;
    float yim = ((v + 1.0f)*0.5f)*959.0f;
    float x0 = floorf(xim), y0 = floorf(yim);
    float ts[7] = {0,0,0,0,0,0,0};
    #pragma unroll
    for (int ty = 0; ty <= 1; ty++) {
        float yy = y0 + (float)ty;
        if (yy < 0.0f || yy > 959.0f) continue;
        float wy = 1.0f - fabsf(yim - yy);
        #pragma unroll
        for (int tx = 0; tx <= 1; tx++) {
            float xx = x0 + (float)tx;
            if (xx < 0.0f || xx > 959.0f) continue;
            float w = (1.0f - fabsf(xim - xx)) * wy;
            // recompute rotated(yy, xx) exactly (bit-identical to materializing it)
            float rot[7] = {0,0,0,0,0,0,0};
            float gx1 = xx*step - 1.0f;
            float gy1 = yy*step - 1.0f;
            sample_agent(gx1, gy1, ct, sn, sm, rot);
            #pragma unroll
            for (int k = 0; k < 7; k++) ts[k] += rot[k]*w;
        }
    }
    int o = t;
    float ml;
    ml = maps_last[0*MPIX + o]; out_map[0*MPIX + o] = fmaxf(ml, ts[0]);
    ml = maps_last[1*MPIX + o]; out_map[1*MPIX + o] = fmaxf(ml, ts[1]);
    ml = maps_last[2*MPIX + o]; out_map[2*MPIX + o] = fmaxf(ml, 0.0f);
    ml = maps_last[3*MPIX + o]; out_map[3*MPIX + o] = fmaxf(ml, 0.0f);
    float t4 = ts[2]; t4 = (t4 > 0.0f) ? ks0 : t4;
    ml = maps_last[4*MPIX + o]; out_map[4*MPIX + o] = fmaxf(ml, t4);
    float t5 = ts[3]; t5 = (t5 > 0.0f) ? ks1 : t5;
    ml = maps_last[5*MPIX + o]; out_map[5*MPIX + o] = fmaxf(ml, t5);
    float t6 = ts[4]; t6 = (t6 > 0.0f) ? ks2 : t6;
    ml = maps_last[6*MPIX + o]; out_map[6*MPIX + o] = fmaxf(ml, t6);
    float t7 = ts[5]; t7 = (t7 > 0.0f) ? ks3 : t7;
    ml = maps_last[7*MPIX + o]; out_map[7*MPIX + o] = fmaxf(ml, t7);
    ml = maps_last[8*MPIX + o]; out_map[8*MPIX + o] = fmaxf(ml, ts[6]);
}

extern "C" void kernel_launch(void* const* d_in, const int* in_sizes, int n_in,
                              void* d_out, int out_size, void* d_ws, size_t ws_size,
                              hipStream_t stream) {
    const float* obs        = (const float*)d_in[0];
    const float* pose_obs   = (const float*)d_in[1];
    const float* maps_last  = (const float*)d_in[2];
    const float* poses_last = (const float*)d_in[3];
    float* out = (float*)d_out;

    size_t small_bytes = (size_t)(SM_FLOATS + SCAL_FLOATS) * 4;
    size_t rep_bytes = (size_t)NVOX * 3 * 8;                 // 19.2 MB per replica
    size_t need_rep  = rep_bytes * NREP + small_bytes;       // ~154 MB
    int nrep = (ws_size >= need_rep) ? NREP : 1;
    size_t grid_bytes = rep_bytes * nrep;

    unsigned long long* grid = (unsigned long long*)d_ws;
    float* sm   = (float*)((char*)d_ws + grid_bytes);
    float* scal = sm + SM_FLOATS;

    // zero grid replicas + small maps + scalars (ws is poisoned 0xAA each launch)
    hipMemsetAsync(d_ws, 0, grid_bytes + small_bytes, stream);

    float fcam = (float)(320.0 / tan(39.5 * M_PI / 180.0));

    pose_kernel<<<1, 64, 0, stream>>>(pose_obs, poses_last, scal, out + OUT_POSE);
    ks_kernel<<<128, 256, 0, stream>>>(obs, scal);
    if (nrep == NREP)
        splat_kernel_rep<<<(NPIX + 255)/256, 256, 0, stream>>>(obs, grid, fcam);
    else
        splat_kernel<<<(NPIX + 255)/256, 256, 0, stream>>>(obs, grid, fcam);
    reduce_kernel<<<(10000 + 255)/256, 256, 0, stream>>>(grid, sm, out + OUT_FPMAP, nrep);
    final_kernel<<<(MPIX + 255)/256, 256, 0, stream>>>(maps_last, sm, scal, out + OUT_MAP);
}

// Round 4
// 276.329 us; speedup vs baseline: 2.1313x; 2.1313x over previous
//
#include <hip/hip_runtime.h>
#include <math.h>

#define NPIX (480*640)
#define MDIM 960
#define MPIX (MDIM*MDIM)

// ws layout (u32/float units from base)
#define CNT_OFF   0          // u32[10000]
#define CUR_OFF   10000      // u32[10000]
#define SCAL_OFF  20000      // float[16]
#define MEMSET_U32 20016     // zero cnt+cur+scal only
#define OFFS_OFF  20016      // u32[10008]
#define SM_OFF    30024      // float[70000]: 7 planes * 10000
#define PAY_OFF   100024     // float[8*NPIX], 16B-aligned (100024*4 % 16 == 0)

// output layout (floats)
#define OUT_FPMAP 0
#define OUT_MAP   10000
#define OUT_POSE  (10000 + 9*MPIX)

__global__ void pose_kernel(const float* pose_obs, const float* poses_last,
                            float* scal, float* out_pose) {
    if (threadIdx.x == 0) {
        const float DEGc = 57.29577951308232f;
        float th = poses_last[2] / DEGc;
        float s = sinf(th), c = cosf(th);
        float ny = poses_last[1] + pose_obs[0]*s + pose_obs[1]*c;
        float nx = poses_last[0] + pose_obs[0]*c - pose_obs[1]*s;
        float nt = poses_last[2] + pose_obs[2]*DEGc;
        nt = fmodf(nt - 180.0f, 360.0f) + 180.0f;
        nt = fmodf(nt + 180.0f, 360.0f) - 180.0f;
        out_pose[0] = nx; out_pose[1] = ny; out_pose[2] = nt;
        out_pose[3] = nx; out_pose[4] = ny; out_pose[5] = nt;
        float sx = -((nx*100.0f)/5.0f - 480.0f)/480.0f;
        float sy = -((ny*100.0f)/5.0f - 480.0f)/480.0f;
        float sth = ((90.0f - nt) * 3.14159265358979323846f) / 180.0f;
        scal[0] = cosf(sth);
        scal[1] = sinf(sth);
        scal[2] = sx;
        scal[3] = sy;
    }
}

__global__ void ks_kernel(const float* __restrict__ obs, float* scal) {
    int tid = blockIdx.x*blockDim.x + threadIdx.x;
    int stride = gridDim.x*blockDim.x;
    float m0 = 0.0f, m1 = 0.0f, m2 = 0.0f, m3 = 0.0f;  // obs values are >= 0
    for (int p = tid; p < NPIX; p += stride) {
        m0 = fmaxf(m0, obs[4*NPIX + p]);
        m1 = fmaxf(m1, obs[5*NPIX + p]);
        m2 = fmaxf(m2, obs[6*NPIX + p]);
        m3 = fmaxf(m3, obs[7*NPIX + p]);
    }
    #pragma unroll
    for (int off = 32; off > 0; off >>= 1) {
        m0 = fmaxf(m0, __shfl_down(m0, off, 64));
        m1 = fmaxf(m1, __shfl_down(m1, off, 64));
        m2 = fmaxf(m2, __shfl_down(m2, off, 64));
        m3 = fmaxf(m3, __shfl_down(m3, off, 64));
    }
    if ((threadIdx.x & 63) == 0) {
        atomicMax((int*)&scal[4], __float_as_int(m0));
        atomicMax((int*)&scal[5], __float_as_int(m1));
        atomicMax((int*)&scal[6], __float_as_int(m2));
        atomicMax((int*)&scal[7], __float_as_int(m3));
    }
}

// exact replica of the reference fp32 position chain (validated rounds 1-3)
__device__ __forceinline__ void pix_pos(const float* __restrict__ obs, int pix, float fcam,
                                        float& pos0, float& pos1, float& pos2) {
    int i = pix / 640, j = pix - i*640;
    float d = obs[3*NPIX + pix];
    float X = ((float)j - 319.5f) * d / fcam + 250.0f;
    float Z = ((float)(479 - i) - 239.5f) * d / fcam + 88.0f;
    float xs = ((X/5.0f - 50.0f)/100.0f)*2.0f;
    float ys = ((d/5.0f - 50.0f)/100.0f)*2.0f;
    float zs = ((Z/5.0f - 32.0f)/80.0f)*2.0f;
    pos0 = (xs*100.0f)/2.0f + 50.0f;
    pos1 = (ys*100.0f)/2.0f + 50.0f;
    pos2 = (zs*80.0f)/2.0f + 40.0f;
}

__global__ __launch_bounds__(256) void count_kernel(const float* __restrict__ obs,
                                                    unsigned* __restrict__ cnt, float fcam) {
    int pix = blockIdx.x*blockDim.x + threadIdx.x;
    if (pix >= NPIX) return;
    float p0, p1, p2;
    pix_pos(obs, pix, fcam, p0, p1, p2);
    int bx = (int)floorf(p0), by = (int)floorf(p1), bz = (int)floorf(p2);
    if (bx < 0 || bx > 99 || by < 0 || by > 99 || bz < 0 || bz > 79) return;
    atomicAdd(&cnt[bx*100 + by], 1u);
}

__global__ __launch_bounds__(1024) void scan_kernel(const unsigned* __restrict__ cnt,
                                                    unsigned* __restrict__ offs) {
    __shared__ unsigned part[1024];
    int tid = threadIdx.x;
    int base = tid * 10;
    unsigned local[10];
    unsigned s = 0;
    #pragma unroll
    for (int q = 0; q < 10; q++) {
        unsigned v = (base + q < 10000) ? cnt[base + q] : 0u;
        local[q] = s;
        s += v;
    }
    part[tid] = s;
    __syncthreads();
    // Hillis-Steele inclusive scan over 1024 partials
    for (int off = 1; off < 1024; off <<= 1) {
        unsigned v = (tid >= off) ? part[tid - off] : 0u;
        __syncthreads();
        part[tid] += v;
        __syncthreads();
    }
    unsigned chunk_excl = (tid > 0) ? part[tid - 1] : 0u;
    #pragma unroll
    for (int q = 0; q < 10; q++) {
        if (base + q <= 10000) offs[base + q] = chunk_excl + local[q];
    }
}

__global__ __launch_bounds__(256) void scatter_kernel(const float* __restrict__ obs,
                                                      const unsigned* __restrict__ offs,
                                                      unsigned* __restrict__ cur,
                                                      float4* __restrict__ pay, float fcam) {
    int pix = blockIdx.x*blockDim.x + threadIdx.x;
    if (pix >= NPIX) return;
    float p0, p1, p2;
    pix_pos(obs, pix, fcam, p0, p1, p2);
    int bx = (int)floorf(p0), by = (int)floorf(p1), bz = (int)floorf(p2);
    if (bx < 0 || bx > 99 || by < 0 || by > 99 || bz < 0 || bz > 79) return;
    int b = bx*100 + by;
    unsigned slot = atomicAdd(&cur[b], 1u);
    unsigned k = offs[b] + slot;
    float f1 = obs[4*NPIX + pix];
    float f2 = obs[5*NPIX + pix];
    float f3 = obs[6*NPIX + pix];
    float f4 = obs[7*NPIX + pix];
    float f5 = obs[8*NPIX + pix];
    pay[2*k + 0] = make_float4(p0, p1, p2, f1);
    pay[2*k + 1] = make_float4(f2, f3, f4, f5);
}

// one 64-lane workgroup per voxel column (x,y); LDS z-slab accumulation, fused reduce
__global__ __launch_bounds__(64) void gather_kernel(const float4* __restrict__ pay,
                                                    const unsigned* __restrict__ offs,
                                                    float* __restrict__ sm,
                                                    float* __restrict__ out_fp) {
    int t = blockIdx.x;              // t = y*100 + x (matches sm indexing)
    int x = t % 100, y = t / 100;
    int lane = threadIdx.x;
    __shared__ float zacc[80*6];
    for (int q = lane; q < 480; q += 64) zacc[q] = 0.0f;
    __syncthreads();
    if (x >= 1 && y >= 1) {          // column 0 in either dim receives nothing (safe=0)
        for (int bx = x-1; bx <= x; bx++) {
            for (int by = y-1; by <= y; by++) {
                int b = bx*100 + by;
                unsigned s = offs[b], e = offs[b+1];
                for (unsigned k = s + lane; k < e; k += 64) {
                    float4 a  = pay[2*k + 0];
                    float4 q2 = pay[2*k + 1];
                    // weights replicate reference order: ((1*(1-|d0|))*(1-|d1|))*(1-|d2|)
                    float w0 = 1.0f - fabsf(a.x - (float)x);
                    float w1 = 1.0f - fabsf(a.y - (float)y);
                    float w01 = w0 * w1;
                    float bzf = floorf(a.z);
                    #pragma unroll
                    for (int c2 = 0; c2 <= 1; c2++) {
                        float p2 = bzf + (float)c2;
                        if (!(p2 > 0.0f && p2 < 80.0f)) continue;
                        float w = w01 * (1.0f - fabsf(a.z - p2));
                        int zb = (int)p2 * 6;
                        atomicAdd(&zacc[zb + 0], w);
                        atomicAdd(&zacc[zb + 1], w*a.w);
                        atomicAdd(&zacc[zb + 2], w*q2.x);
                        atomicAdd(&zacc[zb + 3], w*q2.y);
                        atomicAdd(&zacc[zb + 4], w*q2.z);
                        atomicAdd(&zacc[zb + 5], w*q2.w);
                    }
                }
            }
        }
    }
    __syncthreads();
    // per-z round, then column sums (exact: summands are small integers)
    int z = lane;                    // z in [0,64); z in [64,80) handled by lanes 0..15
    float r0 = rintf(zacc[z*6 + 0]);
    float all0 = r0;
    if (lane < 16) all0 += rintf(zacc[(z + 64)*6 + 0]);
    bool inb = (z >= 13 && z < 25);
    float a0 = inb ? r0 : 0.0f;
    float a1 = inb ? rintf(zacc[z*6 + 1]) : 0.0f;
    float a2 = inb ? rintf(zacc[z*6 + 2]) : 0.0f;
    float a3 = inb ? rintf(zacc[z*6 + 3]) : 0.0f;
    float a4 = inb ? rintf(zacc[z*6 + 4]) : 0.0f;
    float a5 = inb ? rintf(zacc[z*6 + 5]) : 0.0f;
    #pragma unroll
    for (int off = 32; off > 0; off >>= 1) {
        all0 += __shfl_down(all0, off, 64);
        a0 += __shfl_down(a0, off, 64);
        a1 += __shfl_down(a1, off, 64);
        a2 += __shfl_down(a2, off, 64);
        a3 += __shfl_down(a3, off, 64);
        a4 += __shfl_down(a4, off, 64);
        a5 += __shfl_down(a5, off, 64);
    }
    if (lane == 0) {
        float fp = fminf(a0, 1.0f);
        float ex = fminf(all0, 1.0f);
        sm[0*10000 + t] = fp;
        sm[1*10000 + t] = ex;
        sm[2*10000 + t] = fminf(a1/5.0f, 1.0f);
        sm[3*10000 + t] = fminf(a2/5.0f, 1.0f);
        sm[4*10000 + t] = fminf(a3/5.0f, 1.0f);
        sm[5*10000 + t] = fminf(a4/5.0f, 1.0f);
        sm[6*10000 + t] = fminf(a5/5.0f, 1.0f);
        out_fp[t] = fp;
    }
}

// bilinear sample of the (implicit, mostly-zero) agent_view at normalized coords,
// accumulating the 7 nonzero channels [0,1,4,5,6,7,8] from the small maps.
__device__ __forceinline__ void sample_agent(float gxv, float gyv,
                                             float ct, float sn,
                                             const float* __restrict__ sm,
                                             float rot[7]) {
    float u = ct*gxv - sn*gyv;
    float v = sn*gxv + ct*gyv;
    float xim = ((u + 1.0f)*0.5f)*959.0f;
    float yim = ((v + 1.0f)*0.5f)*959.0f;
    float x0 = floorf(xim), y0 = floorf(yim);
    #pragma unroll
    for (int ty = 0; ty <= 1; ty++) {
        float yy = y0 + (float)ty;
        if (yy < 480.0f || yy >= 580.0f) continue;   // region rows [480,580)
        float wy = 1.0f - fabsf(yim - yy);
        int yi = (int)yy - 480;
        #pragma unroll
        for (int tx = 0; tx <= 1; tx++) {
            float xx = x0 + (float)tx;
            if (xx < 430.0f || xx >= 530.0f) continue;  // region cols [430,530)
            float w = (1.0f - fabsf(xim - xx)) * wy;
            int o = yi*100 + ((int)xx - 430);
            #pragma unroll
            for (int k = 0; k < 7; k++) rot[k] += sm[k*10000 + o] * w;
        }
    }
}

__global__ __launch_bounds__(256) void final_kernel(const float* __restrict__ maps_last,
                                                    const float* __restrict__ sm,
                                                    const float* __restrict__ scal,
                                                    float* __restrict__ out_map) {
    int t = blockIdx.x*blockDim.x + threadIdx.x;
    if (t >= MPIX) return;
    int y = t / MDIM, x = t - y*MDIM;
    float ct = scal[0], sn = scal[1], sx = scal[2], sy = scal[3];
    float ks0 = scal[4], ks1 = scal[5], ks2 = scal[6], ks3 = scal[7];
    const float step = 2.0f/959.0f;
    float gxv = (float)x*step - 1.0f;
    float gyv = (float)y*step - 1.0f;
    float u = gxv + sx, v = gyv + sy;
    float xim = ((u + 1.0f)*0.5f)*959.0f;
    float yim = ((v + 1.0f)*0.5f)*959.0f;
    float x0 = floorf(xim), y0 = floorf(yim);
    float ts[7] = {0,0,0,0,0,0,0};
    #pragma unroll
    for (int ty = 0; ty <= 1; ty++) {
        float yy = y0 + (float)ty;
        if (yy < 0.0f || yy > 959.0f) continue;
        float wy = 1.0f - fabsf(yim - yy);
        #pragma unroll
        for (int tx = 0; tx <= 1; tx++) {
            float xx = x0 + (float)tx;
            if (xx < 0.0f || xx > 959.0f) continue;
            float w = (1.0f - fabsf(xim - xx)) * wy;
            // recompute rotated(yy, xx) exactly (bit-identical to materializing it)
            float rot[7] = {0,0,0,0,0,0,0};
            float gx1 = xx*step - 1.0f;
            float gy1 = yy*step - 1.0f;
            sample_agent(gx1, gy1, ct, sn, sm, rot);
            #pragma unroll
            for (int k = 0; k < 7; k++) ts[k] += rot[k]*w;
        }
    }
    int o = t;
    float ml;
    ml = maps_last[0*MPIX + o]; out_map[0*MPIX + o] = fmaxf(ml, ts[0]);
    ml = maps_last[1*MPIX + o]; out_map[1*MPIX + o] = fmaxf(ml, ts[1]);
    ml = maps_last[2*MPIX + o]; out_map[2*MPIX + o] = fmaxf(ml, 0.0f);
    ml = maps_last[3*MPIX + o]; out_map[3*MPIX + o] = fmaxf(ml, 0.0f);
    float t4 = ts[2]; t4 = (t4 > 0.0f) ? ks0 : t4;
    ml = maps_last[4*MPIX + o]; out_map[4*MPIX + o] = fmaxf(ml, t4);
    float t5 = ts[3]; t5 = (t5 > 0.0f) ? ks1 : t5;
    ml = maps_last[5*MPIX + o]; out_map[5*MPIX + o] = fmaxf(ml, t5);
    float t6 = ts[4]; t6 = (t6 > 0.0f) ? ks2 : t6;
    ml = maps_last[6*MPIX + o]; out_map[6*MPIX + o] = fmaxf(ml, t6);
    float t7 = ts[5]; t7 = (t7 > 0.0f) ? ks3 : t7;
    ml = maps_last[7*MPIX + o]; out_map[7*MPIX + o] = fmaxf(ml, t7);
    ml = maps_last[8*MPIX + o]; out_map[8*MPIX + o] = fmaxf(ml, ts[6]);
}

extern "C" void kernel_launch(void* const* d_in, const int* in_sizes, int n_in,
                              void* d_out, int out_size, void* d_ws, size_t ws_size,
                              hipStream_t stream) {
    const float* obs        = (const float*)d_in[0];
    const float* pose_obs   = (const float*)d_in[1];
    const float* maps_last  = (const float*)d_in[2];
    const float* poses_last = (const float*)d_in[3];
    float* out = (float*)d_out;

    unsigned* ws_u = (unsigned*)d_ws;
    float*    ws_f = (float*)d_ws;
    unsigned* cnt  = ws_u + CNT_OFF;
    unsigned* cur  = ws_u + CUR_OFF;
    float*    scal = ws_f + SCAL_OFF;
    unsigned* offs = ws_u + OFFS_OFF;
    float*    sm   = ws_f + SM_OFF;
    float4*   pay  = (float4*)(ws_f + PAY_OFF);

    // zero cnt + cur + scal (80 KB; ws is poisoned 0xAA each launch)
    hipMemsetAsync(d_ws, 0, (size_t)MEMSET_U32 * 4, stream);

    float fcam = (float)(320.0 / tan(39.5 * M_PI / 180.0));

    pose_kernel<<<1, 64, 0, stream>>>(pose_obs, poses_last, scal, out + OUT_POSE);
    ks_kernel<<<128, 256, 0, stream>>>(obs, scal);
    count_kernel<<<(NPIX + 255)/256, 256, 0, stream>>>(obs, cnt, fcam);
    scan_kernel<<<1, 1024, 0, stream>>>(cnt, offs);
    scatter_kernel<<<(NPIX + 255)/256, 256, 0, stream>>>(obs, offs, cur, pay, fcam);
    gather_kernel<<<10000, 64, 0, stream>>>(pay, offs, sm, out + OUT_FPMAP);
    final_kernel<<<(MPIX + 255)/256, 256, 0, stream>>>(maps_last, sm, scal, out + OUT_MAP);
}

// Round 5
// 266.629 us; speedup vs baseline: 2.2088x; 1.0364x over previous
//
#include <hip/hip_runtime.h>
#include <math.h>

#define NPIX (480*640)
#define MDIM 960
#define MPIX (MDIM*MDIM)

// ws layout (u32/float units from base)
#define CNT_OFF   0          // u32[10000]
#define CUR_OFF   10000      // u32[10000]
#define SCAL_OFF  20000      // float[16]
#define MEMSET_U32 20016     // zero cnt+cur+scal only
#define OFFS_OFF  20016      // u32[10008]
#define SM_OFF    30024      // float[70000]: 7 planes * 10000
#define PAY_OFF   100024     // float[8*NPIX], 16B-aligned (100024*4 % 16 == 0)

// output layout (floats)
#define OUT_FPMAP 0
#define OUT_MAP   10000
#define OUT_POSE  (10000 + 9*MPIX)

__global__ void pose_kernel(const float* pose_obs, const float* poses_last,
                            float* scal, float* out_pose) {
    if (threadIdx.x == 0) {
        const float DEGc = 57.29577951308232f;
        float th = poses_last[2] / DEGc;
        float s = sinf(th), c = cosf(th);
        float ny = poses_last[1] + pose_obs[0]*s + pose_obs[1]*c;
        float nx = poses_last[0] + pose_obs[0]*c - pose_obs[1]*s;
        float nt = poses_last[2] + pose_obs[2]*DEGc;
        nt = fmodf(nt - 180.0f, 360.0f) + 180.0f;
        nt = fmodf(nt + 180.0f, 360.0f) - 180.0f;
        out_pose[0] = nx; out_pose[1] = ny; out_pose[2] = nt;
        out_pose[3] = nx; out_pose[4] = ny; out_pose[5] = nt;
        float sx = -((nx*100.0f)/5.0f - 480.0f)/480.0f;
        float sy = -((ny*100.0f)/5.0f - 480.0f)/480.0f;
        float sth = ((90.0f - nt) * 3.14159265358979323846f) / 180.0f;
        scal[0] = cosf(sth);
        scal[1] = sinf(sth);
        scal[2] = sx;
        scal[3] = sy;
    }
}

__global__ void ks_kernel(const float* __restrict__ obs, float* scal) {
    int tid = blockIdx.x*blockDim.x + threadIdx.x;
    int stride = gridDim.x*blockDim.x;
    float m0 = 0.0f, m1 = 0.0f, m2 = 0.0f, m3 = 0.0f;  // obs values are >= 0
    for (int p = tid; p < NPIX; p += stride) {
        m0 = fmaxf(m0, obs[4*NPIX + p]);
        m1 = fmaxf(m1, obs[5*NPIX + p]);
        m2 = fmaxf(m2, obs[6*NPIX + p]);
        m3 = fmaxf(m3, obs[7*NPIX + p]);
    }
    #pragma unroll
    for (int off = 32; off > 0; off >>= 1) {
        m0 = fmaxf(m0, __shfl_down(m0, off, 64));
        m1 = fmaxf(m1, __shfl_down(m1, off, 64));
        m2 = fmaxf(m2, __shfl_down(m2, off, 64));
        m3 = fmaxf(m3, __shfl_down(m3, off, 64));
    }
    if ((threadIdx.x & 63) == 0) {
        atomicMax((int*)&scal[4], __float_as_int(m0));
        atomicMax((int*)&scal[5], __float_as_int(m1));
        atomicMax((int*)&scal[6], __float_as_int(m2));
        atomicMax((int*)&scal[7], __float_as_int(m3));
    }
}

// exact replica of the reference fp32 position chain (validated rounds 1-4)
__device__ __forceinline__ void pix_pos(const float* __restrict__ obs, int pix, float fcam,
                                        float& pos0, float& pos1, float& pos2) {
    int i = pix / 640, j = pix - i*640;
    float d = obs[3*NPIX + pix];
    float X = ((float)j - 319.5f) * d / fcam + 250.0f;
    float Z = ((float)(479 - i) - 239.5f) * d / fcam + 88.0f;
    float xs = ((X/5.0f - 50.0f)/100.0f)*2.0f;
    float ys = ((d/5.0f - 50.0f)/100.0f)*2.0f;
    float zs = ((Z/5.0f - 32.0f)/80.0f)*2.0f;
    pos0 = (xs*100.0f)/2.0f + 50.0f;
    pos1 = (ys*100.0f)/2.0f + 50.0f;
    pos2 = (zs*80.0f)/2.0f + 40.0f;
}

__global__ __launch_bounds__(256) void count_kernel(const float* __restrict__ obs,
                                                    unsigned* __restrict__ cnt, float fcam) {
    int pix = blockIdx.x*blockDim.x + threadIdx.x;
    if (pix >= NPIX) return;
    float p0, p1, p2;
    pix_pos(obs, pix, fcam, p0, p1, p2);
    int bx = (int)floorf(p0), by = (int)floorf(p1), bz = (int)floorf(p2);
    if (bx < 0 || bx > 99 || by < 0 || by > 99 || bz < 0 || bz > 79) return;
    atomicAdd(&cnt[bx*100 + by], 1u);
}

__global__ __launch_bounds__(1024) void scan_kernel(const unsigned* __restrict__ cnt,
                                                    unsigned* __restrict__ offs) {
    __shared__ unsigned part[1024];
    int tid = threadIdx.x;
    int base = tid * 10;
    unsigned local[10];
    unsigned s = 0;
    #pragma unroll
    for (int q = 0; q < 10; q++) {
        unsigned v = (base + q < 10000) ? cnt[base + q] : 0u;
        local[q] = s;
        s += v;
    }
    part[tid] = s;
    __syncthreads();
    // Hillis-Steele inclusive scan over 1024 partials
    for (int off = 1; off < 1024; off <<= 1) {
        unsigned v = (tid >= off) ? part[tid - off] : 0u;
        __syncthreads();
        part[tid] += v;
        __syncthreads();
    }
    unsigned chunk_excl = (tid > 0) ? part[tid - 1] : 0u;
    #pragma unroll
    for (int q = 0; q < 10; q++) {
        if (base + q <= 10000) offs[base + q] = chunk_excl + local[q];
    }
}

__global__ __launch_bounds__(256) void scatter_kernel(const float* __restrict__ obs,
                                                      const unsigned* __restrict__ offs,
                                                      unsigned* __restrict__ cur,
                                                      float4* __restrict__ pay, float fcam) {
    int pix = blockIdx.x*blockDim.x + threadIdx.x;
    if (pix >= NPIX) return;
    float p0, p1, p2;
    pix_pos(obs, pix, fcam, p0, p1, p2);
    int bx = (int)floorf(p0), by = (int)floorf(p1), bz = (int)floorf(p2);
    if (bx < 0 || bx > 99 || by < 0 || by > 99 || bz < 0 || bz > 79) return;
    int b = bx*100 + by;
    unsigned slot = atomicAdd(&cur[b], 1u);
    unsigned k = offs[b] + slot;
    float f1 = obs[4*NPIX + pix];
    float f2 = obs[5*NPIX + pix];
    float f3 = obs[6*NPIX + pix];
    float f4 = obs[7*NPIX + pix];
    float f5 = obs[8*NPIX + pix];
    pay[2*k + 0] = make_float4(p0, p1, p2, f1);
    pay[2*k + 1] = make_float4(f2, f3, f4, f5);
}

// one 256-lane workgroup per voxel column (x,y); the 4 neighbor bins are
// processed by 4 parallel waves (wave w = bin w); LDS z-slab accumulation,
// fused rint + z-reduce.
__global__ __launch_bounds__(256) void gather_kernel(const float4* __restrict__ pay,
                                                     const unsigned* __restrict__ offs,
                                                     float* __restrict__ sm,
                                                     float* __restrict__ out_fp) {
    int t = blockIdx.x;              // t = y*100 + x (matches sm indexing)
    int x = t % 100, y = t / 100;
    int tid = threadIdx.x;
    int sub = tid >> 6;              // 0..3 -> bin (x-1+dx, y-1+dy)
    int lane = tid & 63;
    __shared__ float zacc[80*6];
    for (int q = tid; q < 480; q += 256) zacc[q] = 0.0f;
    __syncthreads();
    if (x >= 1 && y >= 1) {          // column 0 in either dim receives nothing (safe=0)
        int bx = x - 1 + (sub & 1);
        int by = y - 1 + (sub >> 1);
        int b = bx*100 + by;
        unsigned s = offs[b], e = offs[b+1];
        for (unsigned k = s + lane; k < e; k += 64) {
            float4 a  = pay[2*k + 0];
            float4 q2 = pay[2*k + 1];
            // weights replicate reference order: ((1*(1-|d0|))*(1-|d1|))*(1-|d2|)
            float w0 = 1.0f - fabsf(a.x - (float)x);
            float w1 = 1.0f - fabsf(a.y - (float)y);
            float w01 = w0 * w1;
            float bzf = floorf(a.z);
            #pragma unroll
            for (int c2 = 0; c2 <= 1; c2++) {
                float p2 = bzf + (float)c2;
                if (!(p2 > 0.0f && p2 < 80.0f)) continue;
                float w = w01 * (1.0f - fabsf(a.z - p2));
                int zb = (int)p2 * 6;
                atomicAdd(&zacc[zb + 0], w);
                atomicAdd(&zacc[zb + 1], w*a.w);
                atomicAdd(&zacc[zb + 2], w*q2.x);
                atomicAdd(&zacc[zb + 3], w*q2.y);
                atomicAdd(&zacc[zb + 4], w*q2.z);
                atomicAdd(&zacc[zb + 5], w*q2.w);
            }
        }
    }
    __syncthreads();
    if (tid < 64) {
        // per-z round, then column sums (exact: summands are small integers)
        int z = lane;                // z in [0,64); z in [64,80) folded by lanes 0..15
        float r0 = rintf(zacc[z*6 + 0]);
        float all0 = r0;
        if (lane < 16) all0 += rintf(zacc[(z + 64)*6 + 0]);
        bool inb = (z >= 13 && z < 25);
        float a0 = inb ? r0 : 0.0f;
        float a1 = inb ? rintf(zacc[z*6 + 1]) : 0.0f;
        float a2 = inb ? rintf(zacc[z*6 + 2]) : 0.0f;
        float a3 = inb ? rintf(zacc[z*6 + 3]) : 0.0f;
        float a4 = inb ? rintf(zacc[z*6 + 4]) : 0.0f;
        float a5 = inb ? rintf(zacc[z*6 + 5]) : 0.0f;
        #pragma unroll
        for (int off = 32; off > 0; off >>= 1) {
            all0 += __shfl_down(all0, off, 64);
            a0 += __shfl_down(a0, off, 64);
            a1 += __shfl_down(a1, off, 64);
            a2 += __shfl_down(a2, off, 64);
            a3 += __shfl_down(a3, off, 64);
            a4 += __shfl_down(a4, off, 64);
            a5 += __shfl_down(a5, off, 64);
        }
        if (lane == 0) {
            float fp = fminf(a0, 1.0f);
            float ex = fminf(all0, 1.0f);
            sm[0*10000 + t] = fp;
            sm[1*10000 + t] = ex;
            sm[2*10000 + t] = fminf(a1/5.0f, 1.0f);
            sm[3*10000 + t] = fminf(a2/5.0f, 1.0f);
            sm[4*10000 + t] = fminf(a3/5.0f, 1.0f);
            sm[5*10000 + t] = fminf(a4/5.0f, 1.0f);
            sm[6*10000 + t] = fminf(a5/5.0f, 1.0f);
            out_fp[t] = fp;
        }
    }
}

// bilinear sample of the (implicit, mostly-zero) agent_view at normalized coords,
// accumulating the 7 nonzero channels [0,1,4,5,6,7,8] from the small maps.
__device__ __forceinline__ void sample_agent(float gxv, float gyv,
                                             float ct, float sn,
                                             const float* __restrict__ sm,
                                             float rot[7]) {
    float u = ct*gxv - sn*gyv;
    float v = sn*gxv + ct*gyv;
    float xim = ((u + 1.0f)*0.5f)*959.0f;
    float yim = ((v + 1.0f)*0.5f)*959.0f;
    float x0 = floorf(xim), y0 = floorf(yim);
    #pragma unroll
    for (int ty = 0; ty <= 1; ty++) {
        float yy = y0 + (float)ty;
        if (yy < 480.0f || yy >= 580.0f) continue;   // region rows [480,580)
        float wy = 1.0f - fabsf(yim - yy);
        int yi = (int)yy - 480;
        #pragma unroll
        for (int tx = 0; tx <= 1; tx++) {
            float xx = x0 + (float)tx;
            if (xx < 430.0f || xx >= 530.0f) continue;  // region cols [430,530)
            float w = (1.0f - fabsf(xim - xx)) * wy;
            int o = yi*100 + ((int)xx - 430);
            #pragma unroll
            for (int k = 0; k < 7; k++) rot[k] += sm[k*10000 + o] * w;
        }
    }
}

__global__ __launch_bounds__(256) void final_kernel(const float* __restrict__ maps_last,
                                                    const float* __restrict__ sm,
                                                    const float* __restrict__ scal,
                                                    float* __restrict__ out_map) {
    int t = blockIdx.x*blockDim.x + threadIdx.x;
    if (t >= MPIX) return;
    int y = t / MDIM, x = t - y*MDIM;
    float ct = scal[0], sn = scal[1], sx = scal[2], sy = scal[3];
    float ks0 = scal[4], ks1 = scal[5], ks2 = scal[6], ks3 = scal[7];
    const float step = 2.0f/959.0f;
    float gxv = (float)x*step - 1.0f;
    float gyv = (float)y*step - 1.0f;
    float u = gxv + sx, v = gyv + sy;
    float xim = ((u + 1.0f)*0.5f)*959.0f;
    float yim = ((v + 1.0f)*0.5f)*959.0f;
    float ts[7] = {0,0,0,0,0,0,0};

    // Early reject: rotation is an isometry; the 4 translation taps lie within
    // sqrt(2) px of the continuous tap center, so if the rotated center is
    // >1.5 px outside the active window (rows (479,580), cols (429,530)) every
    // sampled value is exactly 0.0f and ts stays exactly zero.
    float gxc = xim*step - 1.0f;
    float gyc = yim*step - 1.0f;
    float uc = ct*gxc - sn*gyc;
    float vc = sn*gxc + ct*gyc;
    float xc2 = ((uc + 1.0f)*0.5f)*959.0f;
    float yc2 = ((vc + 1.0f)*0.5f)*959.0f;
    bool active = (xc2 > 427.5f) && (xc2 < 531.5f) && (yc2 > 477.5f) && (yc2 < 581.5f);

    if (active) {
        float x0 = floorf(xim), y0 = floorf(yim);
        #pragma unroll
        for (int ty = 0; ty <= 1; ty++) {
            float yy = y0 + (float)ty;
            if (yy < 0.0f || yy > 959.0f) continue;
            float wy = 1.0f - fabsf(yim - yy);
            #pragma unroll
            for (int tx = 0; tx <= 1; tx++) {
                float xx = x0 + (float)tx;
                if (xx < 0.0f || xx > 959.0f) continue;
                float w = (1.0f - fabsf(xim - xx)) * wy;
                // recompute rotated(yy, xx) exactly (bit-identical to materializing it)
                float rot[7] = {0,0,0,0,0,0,0};
                float gx1 = xx*step - 1.0f;
                float gy1 = yy*step - 1.0f;
                sample_agent(gx1, gy1, ct, sn, sm, rot);
                #pragma unroll
                for (int k = 0; k < 7; k++) ts[k] += rot[k]*w;
            }
        }
    }
    int o = t;
    float ml;
    ml = maps_last[0*MPIX + o]; out_map[0*MPIX + o] = fmaxf(ml, ts[0]);
    ml = maps_last[1*MPIX + o]; out_map[1*MPIX + o] = fmaxf(ml, ts[1]);
    ml = maps_last[2*MPIX + o]; out_map[2*MPIX + o] = fmaxf(ml, 0.0f);
    ml = maps_last[3*MPIX + o]; out_map[3*MPIX + o] = fmaxf(ml, 0.0f);
    float t4 = ts[2]; t4 = (t4 > 0.0f) ? ks0 : t4;
    ml = maps_last[4*MPIX + o]; out_map[4*MPIX + o] = fmaxf(ml, t4);
    float t5 = ts[3]; t5 = (t5 > 0.0f) ? ks1 : t5;
    ml = maps_last[5*MPIX + o]; out_map[5*MPIX + o] = fmaxf(ml, t5);
    float t6 = ts[4]; t6 = (t6 > 0.0f) ? ks2 : t6;
    ml = maps_last[6*MPIX + o]; out_map[6*MPIX + o] = fmaxf(ml, t6);
    float t7 = ts[5]; t7 = (t7 > 0.0f) ? ks3 : t7;
    ml = maps_last[7*MPIX + o]; out_map[7*MPIX + o] = fmaxf(ml, t7);
    ml = maps_last[8*MPIX + o]; out_map[8*MPIX + o] = fmaxf(ml, ts[6]);
}

extern "C" void kernel_launch(void* const* d_in, const int* in_sizes, int n_in,
                              void* d_out, int out_size, void* d_ws, size_t ws_size,
                              hipStream_t stream) {
    const float* obs        = (const float*)d_in[0];
    const float* pose_obs   = (const float*)d_in[1];
    const float* maps_last  = (const float*)d_in[2];
    const float* poses_last = (const float*)d_in[3];
    float* out = (float*)d_out;

    unsigned* ws_u = (unsigned*)d_ws;
    float*    ws_f = (float*)d_ws;
    unsigned* cnt  = ws_u + CNT_OFF;
    unsigned* cur  = ws_u + CUR_OFF;
    float*    scal = ws_f + SCAL_OFF;
    unsigned* offs = ws_u + OFFS_OFF;
    float*    sm   = ws_f + SM_OFF;
    float4*   pay  = (float4*)(ws_f + PAY_OFF);

    // zero cnt + cur + scal (80 KB; ws is poisoned 0xAA each launch)
    hipMemsetAsync(d_ws, 0, (size_t)MEMSET_U32 * 4, stream);

    float fcam = (float)(320.0 / tan(39.5 * M_PI / 180.0));

    pose_kernel<<<1, 64, 0, stream>>>(pose_obs, poses_last, scal, out + OUT_POSE);
    ks_kernel<<<128, 256, 0, stream>>>(obs, scal);
    count_kernel<<<(NPIX + 255)/256, 256, 0, stream>>>(obs, cnt, fcam);
    scan_kernel<<<1, 1024, 0, stream>>>(cnt, offs);
    scatter_kernel<<<(NPIX + 255)/256, 256, 0, stream>>>(obs, offs, cur, pay, fcam);
    gather_kernel<<<10000, 256, 0, stream>>>(pay, offs, sm, out + OUT_FPMAP);
    final_kernel<<<(MPIX + 255)/256, 256, 0, stream>>>(maps_last, sm, scal, out + OUT_MAP);
}